// Round 1
// baseline (750.697 us; speedup 1.0000x reference)
//
#include <hip/hip_runtime.h>

#define KS 51
#define RAD 25
#define DIM 128
#define NIMG 2048          // B*DIM = 16*128
#define HW 64
#define WROW 64            // padded weight row stride (floats) -> 256B rows
#define XSTRIDE 120        // padded LDS row stride (floats)
#define XROWS 114          // 64 + 2*25

// Combined per-channel dense kernels, [c][ki][0..63] (kj >= 51 zeroed).
__device__ float g_weights[DIM * KS * WROW];

// Map signed offset o in [-25,25] to peripheral index 0..12.
// coords = [0,1,2,4,8,16,25]; quantise = largest coord <= |o|.
__device__ __forceinline__ int qidx(int o) {
  int a = o < 0 ? -o : o;
  int r;
  if (a >= 25)      r = 6;
  else if (a >= 16) r = 5;
  else if (a >= 8)  r = 4;
  else if (a >= 4)  r = 3;
  else if (a >= 2)  r = 2;
  else              r = a;   // 0 -> 0, 1 -> 1
  return o < 0 ? 6 - r : 6 + r;
}

__global__ void prep_weights(const float* __restrict__ comp,
                             const float* __restrict__ kpe) {
  const int c = blockIdx.x;
  const float* crow = comp + c * 169;           // P*P = 13*13
  float* wrow = g_weights + c * KS * WROW;
  for (int t = threadIdx.x; t < KS * WROW; t += blockDim.x) {
    const int ki = t >> 6, kj = t & 63;
    float v = 0.f;
    if (kj < KS) {
      const int idx = qidx(ki - RAD) * 13 + qidx(kj - RAD);
      v = crow[idx] + kpe[ki * KS + kj];
    }
    wrow[t] = v;
  }
}

__launch_bounds__(256, 2)
__global__ void dwconv(const float* __restrict__ x, float* __restrict__ out) {
  __shared__ float xs[XROWS * XSTRIDE];         // 54,720 B
  const int img = blockIdx.x;                   // b*128 + c
  const int c   = img & (DIM - 1);
  const int tid = threadIdx.x;

  // Zero the whole padded tile (halo + row pad). LDS is uninitialized.
  const float4 z4 = make_float4(0.f, 0.f, 0.f, 0.f);
  for (int i = tid; i < XROWS * XSTRIDE / 4; i += 256)
    *(float4*)&xs[i * 4] = z4;
  __syncthreads();

  // Fill center: xs[25+r][25+c] = x[r][c]. Center col 25 is not 16B-aligned
  // in LDS -> scalar ds_writes (one-time, cheap); reads stay b128-aligned.
  const float* __restrict__ ximg = x + (size_t)img * (HW * HW);
  {
    const int r = tid >> 2, q = tid & 3;
    const float* src = ximg + r * HW + q * 16;
    float* dst = &xs[(RAD + r) * XSTRIDE + RAD + q * 16];
#pragma unroll
    for (int i = 0; i < 4; ++i) {
      const float4 v = *(const float4*)&src[4 * i];
      dst[4 * i + 0] = v.x; dst[4 * i + 1] = v.y;
      dst[4 * i + 2] = v.z; dst[4 * i + 3] = v.w;
    }
  }
  __syncthreads();

  const int row = tid >> 2;          // 0..63
  const int cb  = (tid & 3) << 4;    // 0,16,32,48
  const float* __restrict__ wbase = g_weights + c * KS * WROW;

  float acc[16];
#pragma unroll
  for (int j = 0; j < 16; ++j) acc[j] = 0.f;

  for (int ki = 0; ki < KS; ++ki) {
    // 68-float register window: cols cb .. cb+67 of padded row (row+ki).
    const float* xr = &xs[(row + ki) * XSTRIDE + cb];
    float W[68];
#pragma unroll
    for (int t = 0; t < 17; ++t)
      *(float4*)&W[4 * t] = *(const float4*)&xr[4 * t];   // ds_read_b128

    const float* __restrict__ wr = wbase + ki * WROW;     // uniform -> s_load
#pragma unroll
    for (int kj = 0; kj < KS; ++kj) {
      const float wv = wr[kj];
#pragma unroll
      for (int j = 0; j < 16; ++j)
        acc[j] = fmaf(wv, W[kj + j], acc[j]);             // v_fmac_f32 v,s,v
    }
  }

  float* orow = out + (size_t)img * (HW * HW) + row * HW + cb;
#pragma unroll
  for (int t = 0; t < 4; ++t)
    *(float4*)&orow[4 * t] =
        make_float4(acc[4 * t], acc[4 * t + 1], acc[4 * t + 2], acc[4 * t + 3]);
}

extern "C" void kernel_launch(void* const* d_in, const int* in_sizes, int n_in,
                              void* d_out, int out_size, void* d_ws, size_t ws_size,
                              hipStream_t stream) {
  const float* x    = (const float*)d_in[0];
  const float* comp = (const float*)d_in[1];
  const float* kpe  = (const float*)d_in[2];
  float* out        = (float*)d_out;

  prep_weights<<<dim3(DIM), dim3(256), 0, stream>>>(comp, kpe);
  dwconv<<<dim3(NIMG), dim3(256), 0, stream>>>(x, out);
}